// Round 4
// baseline (997.731 us; speedup 1.0000x reference)
//
#include <hip/hip_runtime.h>
#include <hip/hip_bf16.h>

// MultiHeadMLP fused kernel for MI355X (gfx950).
// out[b,h,s] = elu(x[b,:] @ W1[h] + b1[h]) @ W2[h] + b2[h]
// Split-bf16 (hi/lo) 3-product MFMA => ~fp32 accuracy.
// GEMM1 computed swapped (W1^T @ x^T) so its accumulator layout IS the
// A-operand layout of GEMM2 (no LDS round-trip for the hidden activations).

typedef __attribute__((ext_vector_type(8))) short bf16x8;     // MFMA A/B frag (4 VGPR)
typedef __attribute__((ext_vector_type(4))) float f32x4;      // MFMA C/D frag
typedef __attribute__((ext_vector_type(4))) unsigned int u32x4;

union frag_u { u32x4 u; bf16x8 b; };

#define MFMA16(A, B, C) __builtin_amdgcn_mfma_f32_16x16x32_bf16((A), (B), (C), 0, 0, 0)

// Split two f32 into packed bf16 hi-word and lo-word (truncation split:
// hi = top 16 bits, lo = bf16(x - hi); combined error ~2^-16 relative).
__device__ __forceinline__ void split2(float a, float b, unsigned &wh, unsigned &wl) {
  unsigned ua = __float_as_uint(a), ub = __float_as_uint(b);
  unsigned ha = ua & 0xFFFF0000u, hb = ub & 0xFFFF0000u;
  float ra = a - __uint_as_float(ha);
  float rb = b - __uint_as_float(hb);
  wh = (ha >> 16) | hb;
  wl = (__float_as_uint(ra) >> 16) | (__float_as_uint(rb) & 0xFFFF0000u);
}

__global__ __launch_bounds__(256, 2)
void mhmlp_kernel(const float* __restrict__ x, const float* __restrict__ W1,
                  const float* __restrict__ b1, const float* __restrict__ W2,
                  const float* __restrict__ b2, float* __restrict__ out) {
  // LDS: W1 hi/lo frags (16KB each), W2 hi/lo frags (16KB each), b1, b2
  __shared__ __align__(16) char smem[66560];
  unsigned short* w1h = (unsigned short*)(smem);
  unsigned short* w1l = (unsigned short*)(smem + 16384);
  unsigned short* w2h = (unsigned short*)(smem + 32768);
  unsigned short* w2l = (unsigned short*)(smem + 49152);
  float* b1s = (float*)(smem + 65536);   // 128 f32
  float* b2s = (float*)(smem + 66048);   // 64 f32

  const int head  = blockIdx.x & 15;
  const int chunk = blockIdx.x >> 4;
  const int tid   = threadIdx.x;
  const int lane  = tid & 63;
  const int wave  = tid >> 6;
  const int q = lane >> 4;    // lane group (0..3)
  const int m = lane & 15;    // lane-in-group (0..15)

  // ---------------- stage weights as pre-permuted bf16 hi/lo fragments ---------------
  // A-frag of GEMM1 (A = W1^T, 16(hid) x 32(in) tiles): frag elem j of lane l at
  // (tile t, kstep s): hid = 16t + (l&15), in = 32s + 16*(j>>2) + 4*(l>>4) + (j&3).
  // B-frag of GEMM2 (B = W2, 32(hid) x 16(out) tiles): out = 16u + (l&15),
  // hid = 32s + 16*(j>>2) + 4*(l>>4) + (j&3).
  const float* W1g = W1 + (size_t)head * 64 * 128;
  const float* W2g = W2 + (size_t)head * 128 * 64;
  #pragma unroll
  for (int kk = 0; kk < 4; ++kk) {
    int cid = tid + 256 * kk;      // 0..1023
    int l   = cid & 63;
    int fid = cid >> 6;            // W1: t*2+s (t<8,s<2); W2: u*4+s (u<4,s<4)
    int lq = l >> 4, lm = l & 15;
    {
      int s = fid & 1, t = fid >> 1;
      u32x4 hw, lw;
      #pragma unroll
      for (int p = 0; p < 4; ++p) {
        int j0 = 2 * p, j1 = j0 + 1;
        int in0 = 32 * s + 16 * (j0 >> 2) + 4 * lq + (j0 & 3);
        int in1 = 32 * s + 16 * (j1 >> 2) + 4 * lq + (j1 & 3);
        float v0 = W1g[in0 * 128 + 16 * t + lm];
        float v1 = W1g[in1 * 128 + 16 * t + lm];
        unsigned a, b; split2(v0, v1, a, b);
        hw[p] = a; lw[p] = b;
      }
      *(u32x4*)(w1h + cid * 8) = hw;
      *(u32x4*)(w1l + cid * 8) = lw;
    }
    {
      int s = fid & 3, u = fid >> 2;
      u32x4 hw, lw;
      #pragma unroll
      for (int p = 0; p < 4; ++p) {
        int j0 = 2 * p, j1 = j0 + 1;
        int k0 = 32 * s + 16 * (j0 >> 2) + 4 * lq + (j0 & 3);
        int k1 = 32 * s + 16 * (j1 >> 2) + 4 * lq + (j1 & 3);
        float v0 = W2g[k0 * 64 + 16 * u + lm];
        float v1 = W2g[k1 * 64 + 16 * u + lm];
        unsigned a, b; split2(v0, v1, a, b);
        hw[p] = a; lw[p] = b;
      }
      *(u32x4*)(w2h + cid * 8) = hw;
      *(u32x4*)(w2l + cid * 8) = lw;
    }
  }
  if (tid < 128) b1s[tid] = b1[head * 128 + tid];
  if (tid < 64)  b2s[tid] = b2[head * 64 + tid];
  __syncthreads();

  // ---------------- main loop: 32 iterations x 128 rows/block (32 rows/wave) --------
  const long rowbase0 = (long)chunk * 4096 + wave * 32;
  for (int it = 0; it < 32; ++it) {
    const long rb = rowbase0 + (long)it * 128;

    // ---- load x (global -> reg, 64B/row coalesced) and split to bf16 hi/lo frags ----
    // B-frag of GEMM1 (B = x^T): batch col = 16b + (l&15),
    // in = 32s + 16*(j>>2) + 4*(l>>4) + (j&3).
    frag_u xh[2][2], xl[2][2];
    #pragma unroll
    for (int b = 0; b < 2; ++b) {
      const float* xp = x + (rb + 16 * b + m) * 64 + 4 * q;
      #pragma unroll
      for (int s = 0; s < 2; ++s) {
        #pragma unroll
        for (int c = 0; c < 2; ++c) {
          f32x4 v = *(const f32x4*)(xp + 32 * s + 16 * c);
          unsigned h0, l0, h1, l1;
          split2(v.x, v.y, h0, l0);
          split2(v.z, v.w, h1, l1);
          xh[b][s].u[2 * c] = h0;     xl[b][s].u[2 * c] = l0;
          xh[b][s].u[2 * c + 1] = h1; xl[b][s].u[2 * c + 1] = l1;
        }
      }
    }

    // ---- GEMM1 (swapped): C1' = W1^T @ x^T, accumulator init = b1 broadcast ----
    // C1' lane layout: hid = 16t + 4q + r, batch = 16b + m.
    f32x4 acc1[8][2];
    #pragma unroll
    for (int t = 0; t < 8; ++t) {
      f32x4 bv = *(const f32x4*)(b1s + t * 16 + q * 4);
      acc1[t][0] = bv; acc1[t][1] = bv;
    }
    #pragma unroll
    for (int s = 0; s < 2; ++s) {
      #pragma unroll
      for (int t = 0; t < 8; ++t) {
        bf16x8 wh = *(const bf16x8*)(w1h + (t * 2 + s) * 512 + lane * 8);
        bf16x8 wl = *(const bf16x8*)(w1l + (t * 2 + s) * 512 + lane * 8);
        #pragma unroll
        for (int b = 0; b < 2; ++b) {
          acc1[t][b] = MFMA16(wh, xh[b][s].b, acc1[t][b]);
          acc1[t][b] = MFMA16(wl, xh[b][s].b, acc1[t][b]);
          acc1[t][b] = MFMA16(wh, xl[b][s].b, acc1[t][b]);
        }
      }
    }

    // ---- ELU + split to GEMM2 A-frags (pure in-register layout chain) ----
    // GEMM2 A-frag (batch 16 x hid-k 32) at kstep s2: frag[j] = acc1[2*s2 + (j>>2)][j&3].
    frag_u a2h[2][4], a2l[2][4];
    #pragma unroll
    for (int b = 0; b < 2; ++b) {
      #pragma unroll
      for (int s2 = 0; s2 < 4; ++s2) {
        float o[8];
        #pragma unroll
        for (int c = 0; c < 2; ++c) {
          #pragma unroll
          for (int r = 0; r < 4; ++r) {
            float v = acc1[2 * s2 + c][b][r];
            float e = exp2f(v * 1.442695040888963f) - 1.0f;   // elu negative branch
            o[4 * c + r] = (v > 0.0f) ? v : e;
          }
        }
        #pragma unroll
        for (int p = 0; p < 4; ++p) {
          unsigned th, tl;
          split2(o[2 * p], o[2 * p + 1], th, tl);
          a2h[b][s2].u[p] = th;
          a2l[b][s2].u[p] = tl;
        }
      }
    }

    // ---- GEMM2: out = A2 @ W2, accumulator init = b2 broadcast ----
    // C2 lane layout: batch = 16b + 4q + r, out = 16u + m.
    f32x4 acc2[4][2];
    #pragma unroll
    for (int u = 0; u < 4; ++u) {
      float bval = b2s[u * 16 + m];
      f32x4 bv = {bval, bval, bval, bval};
      acc2[u][0] = bv; acc2[u][1] = bv;
    }
    #pragma unroll
    for (int s2 = 0; s2 < 4; ++s2) {
      #pragma unroll
      for (int u = 0; u < 4; ++u) {
        bf16x8 wh = *(const bf16x8*)(w2h + (u * 4 + s2) * 512 + lane * 8);
        bf16x8 wl = *(const bf16x8*)(w2l + (u * 4 + s2) * 512 + lane * 8);
        #pragma unroll
        for (int b = 0; b < 2; ++b) {
          acc2[u][b] = MFMA16(a2h[b][s2].b, wh, acc2[u][b]);
          acc2[u][b] = MFMA16(a2l[b][s2].b, wh, acc2[u][b]);
          acc2[u][b] = MFMA16(a2h[b][s2].b, wl, acc2[u][b]);
        }
      }
    }

    // ---- store (4 rows x 64B contiguous per instr) ----
    #pragma unroll
    for (int b = 0; b < 2; ++b) {
      #pragma unroll
      for (int r = 0; r < 4; ++r) {
        long row = rb + 16 * b + 4 * q + r;
        float* op = out + (row * 16 + head) * 64 + m;
        #pragma unroll
        for (int u = 0; u < 4; ++u) op[16 * u] = acc2[u][b][r];
      }
    }
  }
}

extern "C" void kernel_launch(void* const* d_in, const int* in_sizes, int n_in,
                              void* d_out, int out_size, void* d_ws, size_t ws_size,
                              hipStream_t stream) {
  const float* x  = (const float*)d_in[0];
  const float* W1 = (const float*)d_in[1];
  const float* b1 = (const float*)d_in[2];
  const float* W2 = (const float*)d_in[3];
  const float* b2 = (const float*)d_in[4];
  float* out = (float*)d_out;
  int batch  = in_sizes[0] / 64;        // 131072
  int chunks = batch / 4096;            // 32  (32 iters x 128 rows per block)
  mhmlp_kernel<<<dim3(16 * chunks), dim3(256), 0, stream>>>(x, W1, b1, W2, b2, out);
}